// Round 8
// baseline (65207.025 us; speedup 1.0000x reference)
//
#include <hip/hip_runtime.h>
#include <stdint.h>

#define BATCH 256
#define SEQT  512
#define DIM   128
#define HID   256
#define G3    768   // 3*HID

typedef unsigned short u16;
typedef unsigned int   u32;
typedef _Float16 f16;
typedef f16 f16x2 __attribute__((ext_vector_type(2)));
typedef u32 u32x2v __attribute__((ext_vector_type(2)));
typedef u32 u32x4v __attribute__((ext_vector_type(4)));
typedef float f32x4v __attribute__((ext_vector_type(4)));

static __device__ __forceinline__ u16 f2h(float f) {
  f16 h = (f16)f; return __builtin_bit_cast(u16, h);
}
static __device__ __forceinline__ float h2f(u16 u) {
  return (float)__builtin_bit_cast(f16, u);
}
static __device__ __forceinline__ float sigm(float v) {
  return 1.f / (1.f + __expf(-v));
}

// 2-MAC f16 dot with f32 accumulate
static __device__ __forceinline__ float dot2f(u32 a, u32 b, float acc) {
#if __has_builtin(__builtin_amdgcn_fdot2)
  return __builtin_amdgcn_fdot2(__builtin_bit_cast(f16x2, a),
                                __builtin_bit_cast(f16x2, b), acc, false);
#else
  f16x2 av = __builtin_bit_cast(f16x2, a), bv = __builtin_bit_cast(f16x2, b);
  return acc + (float)av[0] * (float)bv[0] + (float)av[1] * (float)bv[1];
#endif
}
// 8 MACs, dual accumulator
static __device__ __forceinline__ void dot8q(float& a0, float& a1, u32x4v w, u32x4v a) {
  a0 = dot2f(w.x, a.x, a0);
  a1 = dot2f(w.y, a.y, a1);
  a0 = dot2f(w.z, a.z, a0);
  a1 = dot2f(w.w, a.w, a1);
}

// ---------------- weight fp32 -> f16, chunk-major transpose ----------------
// dst[((q*chunks + j)*256 + c)*8 + e] = f16( src[(q*256+c)*IN + j*8 + e] )
__global__ void convertT(const float* __restrict__ src, u16* __restrict__ dst,
                         int IN, int chunks, int total) {
  int t = blockIdx.x * 256 + threadIdx.x;
  if (t >= total) return;
  int e = t & 7, c = (t >> 3) & 255, r = t >> 11;
  int j = r % chunks, q = r / chunks;
  dst[t] = f2h(src[(size_t)(q * 256 + c) * IN + j * 8 + e]);
}

// ---------------- phase B: memory GRU, 768 threads, one block per batch row ----------------
__launch_bounds__(768)
__global__ void gru_memk(const float* __restrict__ x,
                         const u16* __restrict__ WiT, const u16* __restrict__ WhT,
                         const float* __restrict__ bmi, const float* __restrict__ bmh,
                         u16* __restrict__ mem) {
  const int b = blockIdx.x, tid = threadIdx.x;
  const int q = tid >> 8, c = tid & 255;
  __shared__ __align__(16) u16 xsH[DIM];
  __shared__ __align__(16) u16 hsH[HID];
  __shared__ __align__(16) float rs[HID], zs[HID];

  float Brz = 0.f, Bni = 0.f, Bnh = 0.f;
  if (q < 2) { int rw = q * HID + c; Brz = bmi[rw] + bmh[rw]; }
  else       { int rw = 2 * HID + c; Bni = bmi[rw]; Bnh = bmh[rw]; }
  const u32x4v* wi = (const u32x4v*)WiT + (size_t)q * (DIM / 8) * 256 + c;
  const u32x4v* wh = (const u32x4v*)WhT + (size_t)q * (HID / 8) * 256 + c;
  float hprev = 0.f;
  if (tid < HID) hsH[tid] = 0;
  __syncthreads();

  for (int t = 0; t < SEQT; ++t) {
    if (tid < DIM)
      xsH[tid] = f2h(__builtin_nontemporal_load(x + ((size_t)b * SEQT + t) * DIM + tid));
    __syncthreads();               // xsH ready; hsH stable
    float a0 = 0.f, a1 = 0.f, a2 = 0.f, a3 = 0.f;
    {
      const u32x4v* xa = (const u32x4v*)xsH;
      const u32x4v* ha = (const u32x4v*)hsH;
      u32x4v wA[8], wB[8];
      // x-side: 16 chunks, 2 groups
      #pragma unroll
      for (int g = 0; g < 8; ++g) wA[g] = wi[(size_t)g * 256];
      #pragma unroll
      for (int g = 0; g < 8; ++g) wB[g] = wi[(size_t)(8 + g) * 256];
      #pragma unroll
      for (int g = 0; g < 8; g += 2) {
        dot8q(a0, a1, wA[g], xa[g]);
        dot8q(a2, a3, wA[g + 1], xa[g + 1]);
      }
      #pragma unroll
      for (int g = 0; g < 8; ++g) wA[g] = wh[(size_t)g * 256];
      #pragma unroll
      for (int g = 0; g < 8; g += 2) {
        dot8q(a0, a1, wB[g], xa[8 + g]);
        dot8q(a2, a3, wB[g + 1], xa[8 + g + 1]);
      }
      float ax = (a0 + a1) + (a2 + a3);    // x-side dot complete
      a0 = a1 = a2 = a3 = 0.f;
      // h-side: 32 chunks, 4 groups (first already loading)
      #pragma unroll
      for (int G = 0; G < 4; ++G) {
        if (G + 1 < 4) {
          #pragma unroll
          for (int g = 0; g < 8; ++g) wB[g] = wh[(size_t)((G + 1) * 8 + g) * 256];
        }
        #pragma unroll
        for (int g = 0; g < 8; g += 2) {
          dot8q(a0, a1, wA[g], ha[G * 8 + g]);
          dot8q(a2, a3, wA[g + 1], ha[G * 8 + g + 1]);
        }
        if (G + 1 < 4) {
          #pragma unroll
          for (int g = 0; g < 8; ++g) wA[g] = wB[g];
        }
      }
      float ah = (a0 + a1) + (a2 + a3);
      a0 = ax; a1 = ah;                    // carry across barrier
    }
    if (q < 2) (q ? zs : rs)[c] = sigm(a0 + a1 + Brz);
    __syncthreads();               // rs/zs ready; hsH reads done
    if (q == 2) {
      float nn = tanhf(a0 + Bni + rs[c] * (a1 + Bnh));
      float h = (1.f - zs[c]) * nn + zs[c] * hprev;
      hprev = h;
      hsH[c] = f2h(h);
      mem[((size_t)b * SEQT + t) * HID + c] = f2h(h);
    }
    __syncthreads();               // hsH ready
  }
}

// ---------------- decoder feed-forward cell, ping-pong pipelined ----------------
template <int IN>
static __device__ __forceinline__ void cellT(const u16* __restrict__ inH,
                                             u16* __restrict__ outH,
                                             const u16* __restrict__ WT,
                                             int q, int c,
                                             float Brz, float Bni, float Bnh,
                                             float* __restrict__ rs, float* __restrict__ zs) {
  constexpr int CH = IN / 8;       // chunks per gate row
  constexpr int NG = CH / 8;       // groups of 8
  float a0 = 0.f, a1 = 0.f, a2 = 0.f, a3 = 0.f;
  if (q < 3) {
    const u32x4v* w = (const u32x4v*)WT + (size_t)q * CH * 256 + c;
    const u32x4v* av = (const u32x4v*)inH;
    u32x4v wA[8];
    #pragma unroll
    for (int g = 0; g < 8; ++g) wA[g] = w[(size_t)g * 256];
    #pragma unroll
    for (int G = 0; G < NG; ++G) {
      u32x4v wB[8];
      if (G + 1 < NG) {
        #pragma unroll
        for (int g = 0; g < 8; ++g) wB[g] = w[(size_t)((G + 1) * 8 + g) * 256];
      }
      #pragma unroll
      for (int g = 0; g < 8; g += 2) {
        dot8q(a0, a1, wA[g], av[G * 8 + g]);
        dot8q(a2, a3, wA[g + 1], av[G * 8 + g + 1]);
      }
      if (G + 1 < NG) {
        #pragma unroll
        for (int g = 0; g < 8; ++g) wA[g] = wB[g];
      }
    }
  }
  float a = (a0 + a1) + (a2 + a3);
  if (q < 2) (q ? zs : rs)[c] = sigm(a + Brz);
  __syncthreads();                 // rs/zs ready
  if (q == 2)
    outH[c] = f2h((1.f - zs[c]) * tanhf(a + Bni + rs[c] * Bnh));
  __syncthreads();                 // outH ready
}

// ---------------- phase C: decoder scan, 1024 threads, one block per batch row ----------------
__launch_bounds__(1024)
__global__ void decoderk(const float* __restrict__ x, const u16* __restrict__ memH,
                         const u16* __restrict__ W0T, const u16* __restrict__ W1T,
                         const u16* __restrict__ W2T, const u16* __restrict__ W3T,
                         const u16* __restrict__ W4T,
                         const float* __restrict__ bi0, const float* __restrict__ bh0,
                         const float* __restrict__ bi1, const float* __restrict__ bh1,
                         const float* __restrict__ bi2, const float* __restrict__ bh2,
                         const float* __restrict__ bi3, const float* __restrict__ bh3,
                         const float* __restrict__ bi4, const float* __restrict__ bh4,
                         const float* __restrict__ Wo, const float* __restrict__ bo,
                         float* __restrict__ out) {
  const int b = blockIdx.x, tid = threadIdx.x;
  const int lane = tid & 63, wave = tid >> 6;
  const int q = tid >> 8, c = tid & 255;
  __shared__ __align__(16) u16 kstH[HID];
  __shared__ __align__(16) u16 dvH[DIM + HID];
  __shared__ __align__(16) u16 hAH[HID], hBH[HID];
  __shared__ __align__(16) float rs[HID], zs[HID];
  __shared__ __align__(16) float ppF[512];
  __shared__ __align__(16) f32x4v pvp4[16][64];
  __shared__ float red2[16];

  float Brz[5] = {0,0,0,0,0}, Bni[5] = {0,0,0,0,0}, Bnh[5] = {0,0,0,0,0};
  if (q < 2) {
    int rw = q * HID + c;
    Brz[0] = bi0[rw] + bh0[rw]; Brz[1] = bi1[rw] + bh1[rw]; Brz[2] = bi2[rw] + bh2[rw];
    Brz[3] = bi3[rw] + bh3[rw]; Brz[4] = bi4[rw] + bh4[rw];
  } else if (q == 2) {
    int rw = 2 * HID + c;
    Bni[0] = bi0[rw]; Bnh[0] = bh0[rw]; Bni[1] = bi1[rw]; Bnh[1] = bh1[rw];
    Bni[2] = bi2[rw]; Bnh[2] = bh2[rw]; Bni[3] = bi3[rw]; Bnh[3] = bh3[rw];
    Bni[4] = bi4[rw]; Bnh[4] = bh4[rw];
  }
  float wo0 = 0.f, wo1 = 0.f, wo2 = 0.f, wo3 = 0.f;
  const float bo0 = bo[0];
  if (wave == 0) { wo0 = Wo[lane]; wo1 = Wo[64+lane]; wo2 = Wo[128+lane]; wo3 = Wo[192+lane]; }
  if (tid < HID) kstH[tid] = 0;
  __syncthreads();

  const u16* mb = memH + (size_t)b * SEQT * HID;
  const int p = tid >> 1, hf = tid & 1;      // scores
  const int sg = tid >> 6, cq = tid & 63;    // PV: position-16th, 4-col quad

  for (int t = 0; t < SEQT; ++t) {
    float xr = 0.f;
    if (tid < DIM)
      xr = __builtin_nontemporal_load(x + ((size_t)b * SEQT + t) * DIM + tid);

    // ---- scores (no-max softmax): thread = (position p, half hf) ----
    float s0 = 0.f, s1 = 0.f;
    {
      const u32x4v* mr = (const u32x4v*)(mb + (size_t)p * HID) + hf * 16;
      const u32x4v* kq = ((const u32x4v*)kstH) + hf * 16;
      u32x4v mA[8], mB[8];
      #pragma unroll
      for (int g = 0; g < 8; ++g) mA[g] = mr[g];
      #pragma unroll
      for (int g = 0; g < 8; ++g) mB[g] = mr[8 + g];
      #pragma unroll
      for (int g = 0; g < 8; ++g) dot8q(s0, s1, mA[g], kq[g]);
      #pragma unroll
      for (int g = 0; g < 8; ++g) dot8q(s0, s1, mB[g], kq[8 + g]);
    }
    float s = s0 + s1;
    s += __shfl_xor(s, 1);
    float pw = __expf(s);
    if (!hf) ppF[p] = pw;
    float ls = hf ? 0.f : pw;
    #pragma unroll
    for (int off = 32; off; off >>= 1) ls += __shfl_xor(ls, off);
    if (lane == 0) red2[wave] = ls;
    if (tid < DIM) dvH[tid] = f2h(xr);
    __syncthreads();               // S2: ppF, red2, dv-x

    // ---- PV: thread = (sg, cq): 4 cols, 32 positions (two interleaved 16-halves) ----
    {
      const u32x2v* mc = (const u32x2v*)mb;
      const float* ppg = ppF + sg * 32;
      float cA0=0.f,cA1=0.f,cA2=0.f,cA3=0.f, cB0=0.f,cB1=0.f,cB2=0.f,cB3=0.f;
      #pragma unroll 4
      for (int pj = 0; pj < 16; ++pj) {
        u32x2v vA = mc[(size_t)(sg * 32 + pj) * 64 + cq];
        u32x2v vB = mc[(size_t)(sg * 32 + 16 + pj) * 64 + cq];
        float wA = ppg[pj], wB = ppg[16 + pj];
        f16x2 a0 = __builtin_bit_cast(f16x2, vA.x), a1 = __builtin_bit_cast(f16x2, vA.y);
        f16x2 b0 = __builtin_bit_cast(f16x2, vB.x), b1 = __builtin_bit_cast(f16x2, vB.y);
        cA0 += wA * (float)a0[0]; cA1 += wA * (float)a0[1];
        cA2 += wA * (float)a1[0]; cA3 += wA * (float)a1[1];
        cB0 += wB * (float)b0[0]; cB1 += wB * (float)b0[1];
        cB2 += wB * (float)b1[0]; cB3 += wB * (float)b1[1];
      }
      f32x4v r;
      r.x = cA0 + cB0; r.y = cA1 + cB1; r.z = cA2 + cB2; r.w = cA3 + cB3;
      pvp4[sg][cq] = r;
    }
    __syncthreads();               // S3: pvp
    if (tid < HID) {
      float lsum = red2[0];
      #pragma unroll
      for (int i = 1; i < 16; ++i) lsum += red2[i];
      const float* pv = (const float*)pvp4;
      float ctx = 0.f;
      #pragma unroll
      for (int i = 0; i < 16; ++i) ctx += pv[i * 256 + tid];
      dvH[DIM + tid] = f2h(ctx / lsum);
    }
    __syncthreads();               // S4: dv complete

    // ---- 5 feed-forward GRU cells ----
    cellT<DIM + HID>(dvH, hAH, W0T, q, c, Brz[0], Bni[0], Bnh[0], rs, zs);
    cellT<HID>(hAH, hBH, W1T, q, c, Brz[1], Bni[1], Bnh[1], rs, zs);
    cellT<HID>(hBH, hAH, W2T, q, c, Brz[2], Bni[2], Bnh[2], rs, zs);
    cellT<HID>(hAH, hBH, W3T, q, c, Brz[3], Bni[3], Bnh[3], rs, zs);
    cellT<HID>(hBH, kstH, W4T, q, c, Brz[4], Bni[4], Bnh[4], rs, zs);

    // ---- output layer (wave 0) ----
    if (wave == 0) {
      float acc = h2f(kstH[lane]) * wo0 + h2f(kstH[64 + lane]) * wo1 +
                  h2f(kstH[128 + lane]) * wo2 + h2f(kstH[192 + lane]) * wo3;
      #pragma unroll
      for (int off = 32; off; off >>= 1) acc += __shfl_xor(acc, off);
      if (lane == 0) out[(size_t)b * SEQT + t] = sigm(acc + bo0);
    }
  }
}

// ---------------- host ----------------
extern "C" void kernel_launch(void* const* d_in, const int* in_sizes, int n_in,
                              void* d_out, int out_size, void* d_ws, size_t ws_size,
                              hipStream_t stream) {
  const float* x    = (const float*)d_in[0];
  const float* Wmi  = (const float*)d_in[1];
  const float* Wmh  = (const float*)d_in[2];
  const float* bmi  = (const float*)d_in[3];
  const float* bmh  = (const float*)d_in[4];
  const float* Wd0  = (const float*)d_in[5];
  const float* bi0  = (const float*)d_in[6];
  const float* bh0  = (const float*)d_in[7];
  const float* Wd1  = (const float*)d_in[8];
  const float* bi1  = (const float*)d_in[9];
  const float* bh1  = (const float*)d_in[10];
  const float* Wd2  = (const float*)d_in[11];
  const float* bi2  = (const float*)d_in[12];
  const float* bh2  = (const float*)d_in[13];
  const float* Wk0  = (const float*)d_in[14];
  const float* bik0 = (const float*)d_in[15];
  const float* bhk0 = (const float*)d_in[16];
  const float* Wk1  = (const float*)d_in[17];
  const float* bik1 = (const float*)d_in[18];
  const float* bhk1 = (const float*)d_in[19];
  const float* Wo   = (const float*)d_in[20];
  const float* bo   = (const float*)d_in[21];

  u16* mem = (u16*)d_ws;
  size_t off = (size_t)BATCH * SEQT * HID;     // u16 units
  u16* WmiT = mem + off; off += (size_t)G3 * DIM;
  u16* WmhT = mem + off; off += (size_t)G3 * HID;
  u16* W0T  = mem + off; off += (size_t)G3 * (DIM + HID);
  u16* W1T  = mem + off; off += (size_t)G3 * HID;
  u16* W2T  = mem + off; off += (size_t)G3 * HID;
  u16* W3T  = mem + off; off += (size_t)G3 * HID;
  u16* W4T  = mem + off; off += (size_t)G3 * HID;
  (void)ws_size; (void)in_sizes; (void)n_in; (void)out_size;

  // chunk-major f16 weight transposes
  convertT<<<(G3*DIM + 255) / 256, 256, 0, stream>>>(Wmi, WmiT, DIM, DIM/8, G3*DIM);
  convertT<<<(G3*HID + 255) / 256, 256, 0, stream>>>(Wmh, WmhT, HID, HID/8, G3*HID);
  convertT<<<(G3*(DIM+HID) + 255) / 256, 256, 0, stream>>>(Wd0, W0T, DIM+HID, (DIM+HID)/8, G3*(DIM+HID));
  convertT<<<(G3*HID + 255) / 256, 256, 0, stream>>>(Wd1, W1T, HID, HID/8, G3*HID);
  convertT<<<(G3*HID + 255) / 256, 256, 0, stream>>>(Wd2, W2T, HID, HID/8, G3*HID);
  convertT<<<(G3*HID + 255) / 256, 256, 0, stream>>>(Wk0, W3T, HID, HID/8, G3*HID);
  convertT<<<(G3*HID + 255) / 256, 256, 0, stream>>>(Wk1, W4T, HID, HID/8, G3*HID);

  gru_memk<<<BATCH, 768, 0, stream>>>(x, WmiT, WmhT, bmi, bmh, mem);
  decoderk<<<BATCH, 1024, 0, stream>>>(x, mem, W0T, W1T, W2T, W3T, W4T,
                                       bi0, bh0, bi1, bh1, bi2, bh2,
                                       bik0, bhk0, bik1, bhk1, Wo, bo,
                                       (float*)d_out);
}

// Round 9
// 61806.830 us; speedup vs baseline: 1.0550x; 1.0550x over previous
//
#include <hip/hip_runtime.h>
#include <stdint.h>

#define BATCH 256
#define SEQT  512
#define DIM   128
#define HID   256
#define G3    768   // 3*HID

typedef unsigned short u16;
typedef unsigned int   u32;
typedef _Float16 f16;
typedef f16 f16x2 __attribute__((ext_vector_type(2)));
typedef u32 u32x2v __attribute__((ext_vector_type(2)));
typedef u32 u32x4v __attribute__((ext_vector_type(4)));
typedef float f32x4v __attribute__((ext_vector_type(4)));

static __device__ __forceinline__ u16 f2h(float f) {
  f16 h = (f16)f; return __builtin_bit_cast(u16, h);
}
static __device__ __forceinline__ float h2f(u16 u) {
  return (float)__builtin_bit_cast(f16, u);
}
static __device__ __forceinline__ float sigm(float v) {
  return 1.f / (1.f + __expf(-v));
}

// 2-MAC f16 dot with f32 accumulate
static __device__ __forceinline__ float dot2f(u32 a, u32 b, float acc) {
#if __has_builtin(__builtin_amdgcn_fdot2)
  return __builtin_amdgcn_fdot2(__builtin_bit_cast(f16x2, a),
                                __builtin_bit_cast(f16x2, b), acc, false);
#else
  f16x2 av = __builtin_bit_cast(f16x2, a), bv = __builtin_bit_cast(f16x2, b);
  return acc + (float)av[0] * (float)bv[0] + (float)av[1] * (float)bv[1];
#endif
}
// 8 MACs, dual accumulator
static __device__ __forceinline__ void dot8q(float& a0, float& a1, u32x4v w, u32x4v a) {
  a0 = dot2f(w.x, a.x, a0);
  a1 = dot2f(w.y, a.y, a1);
  a0 = dot2f(w.z, a.z, a0);
  a1 = dot2f(w.w, a.w, a1);
}

// ---------------- weight fp32 -> f16, chunk-major transpose ----------------
// dst[((q*chunks + j)*256 + c)*8 + e] = f16( src[(q*256+c)*IN + j*8 + e] )
__global__ void convertT(const float* __restrict__ src, u16* __restrict__ dst,
                         int IN, int chunks, int total) {
  int t = blockIdx.x * 256 + threadIdx.x;
  if (t >= total) return;
  int e = t & 7, c = (t >> 3) & 255, r = t >> 11;
  int j = r % chunks, q = r / chunks;
  dst[t] = f2h(src[(size_t)(q * 256 + c) * IN + j * 8 + e]);
}

// ---------------- phase B: memory GRU, 768 threads, one block per batch row ----------------
__launch_bounds__(768, 3)
__global__ void gru_memk(const float* __restrict__ x,
                         const u16* __restrict__ WiT, const u16* __restrict__ WhT,
                         const float* __restrict__ bmi, const float* __restrict__ bmh,
                         u16* __restrict__ mem) {
  const int b = blockIdx.x, tid = threadIdx.x;
  const int q = tid >> 8, c = tid & 255;
  __shared__ __align__(16) u16 xsH[DIM];
  __shared__ __align__(16) u16 hsH[HID];
  __shared__ __align__(16) float rs[HID], zs[HID];

  float Brz = 0.f, Bni = 0.f, Bnh = 0.f;
  if (q < 2) { int rw = q * HID + c; Brz = bmi[rw] + bmh[rw]; }
  else       { int rw = 2 * HID + c; Bni = bmi[rw]; Bnh = bmh[rw]; }
  const u32x4v* wi = (const u32x4v*)WiT + (size_t)q * (DIM / 8) * 256 + c;
  const u32x4v* wh = (const u32x4v*)WhT + (size_t)q * (HID / 8) * 256 + c;
  float hprev = 0.f;
  if (tid < HID) hsH[tid] = 0;
  __syncthreads();

  for (int t = 0; t < SEQT; ++t) {
    if (tid < DIM)
      xsH[tid] = f2h(__builtin_nontemporal_load(x + ((size_t)b * SEQT + t) * DIM + tid));
    __syncthreads();               // xsH ready; hsH stable
    float ax, ah;
    {
      const u32x4v* xa = (const u32x4v*)xsH;
      const u32x4v* ha = (const u32x4v*)hsH;
      u32x4v wA[4], wB[4];
      float a0 = 0.f, a1 = 0.f, a2 = 0.f, a3 = 0.f;
      // x-side: 16 chunks, 4 groups of 4, ping-pong
      #pragma unroll
      for (int g = 0; g < 4; ++g) wA[g] = wi[(size_t)g * 256];
      #pragma unroll
      for (int G = 0; G < 4; ++G) {
        u32x4v* cur = (G & 1) ? wB : wA;
        u32x4v* nxt = (G & 1) ? wA : wB;
        if (G < 3) {
          #pragma unroll
          for (int g = 0; g < 4; ++g) nxt[g] = wi[(size_t)((G + 1) * 4 + g) * 256];
        }
        #pragma unroll
        for (int g = 0; g < 4; g += 2) {
          dot8q(a0, a1, cur[g],     xa[G * 4 + g]);
          dot8q(a2, a3, cur[g + 1], xa[G * 4 + g + 1]);
        }
      }
      ax = (a0 + a1) + (a2 + a3);
      a0 = a1 = a2 = a3 = 0.f;
      // h-side: 32 chunks, 8 groups of 4, ping-pong
      #pragma unroll
      for (int g = 0; g < 4; ++g) wA[g] = wh[(size_t)g * 256];
      #pragma unroll
      for (int G = 0; G < 8; ++G) {
        u32x4v* cur = (G & 1) ? wB : wA;
        u32x4v* nxt = (G & 1) ? wA : wB;
        if (G < 7) {
          #pragma unroll
          for (int g = 0; g < 4; ++g) nxt[g] = wh[(size_t)((G + 1) * 4 + g) * 256];
        }
        #pragma unroll
        for (int g = 0; g < 4; g += 2) {
          dot8q(a0, a1, cur[g],     ha[G * 4 + g]);
          dot8q(a2, a3, cur[g + 1], ha[G * 4 + g + 1]);
        }
      }
      ah = (a0 + a1) + (a2 + a3);
    }
    if (q < 2) (q ? zs : rs)[c] = sigm(ax + ah + Brz);
    __syncthreads();               // rs/zs ready; hsH reads done
    if (q == 2) {
      float nn = tanhf(ax + Bni + rs[c] * (ah + Bnh));
      float h = (1.f - zs[c]) * nn + zs[c] * hprev;
      hprev = h;
      hsH[c] = f2h(h);
      mem[((size_t)b * SEQT + t) * HID + c] = f2h(h);
    }
    __syncthreads();               // hsH ready
  }
}

// ---------------- decoder feed-forward cell, 4-wide ping-pong pipeline ----------------
template <int IN>
static __device__ __forceinline__ void cellT(const u16* __restrict__ inH,
                                             u16* __restrict__ outH,
                                             const u16* __restrict__ WT,
                                             int q, int c,
                                             float Brz, float Bni, float Bnh,
                                             float* __restrict__ rs, float* __restrict__ zs) {
  constexpr int CH = IN / 8;       // chunks per gate row
  constexpr int NG = CH / 4;       // groups of 4
  float a0 = 0.f, a1 = 0.f, a2 = 0.f, a3 = 0.f;
  if (q < 3) {
    const u32x4v* w = (const u32x4v*)WT + (size_t)q * CH * 256 + c;
    const u32x4v* av = (const u32x4v*)inH;
    u32x4v wA[4], wB[4];
    #pragma unroll
    for (int g = 0; g < 4; ++g) wA[g] = w[(size_t)g * 256];
    #pragma unroll
    for (int G = 0; G < NG; ++G) {
      u32x4v* cur = (G & 1) ? wB : wA;
      u32x4v* nxt = (G & 1) ? wA : wB;
      if (G + 1 < NG) {
        #pragma unroll
        for (int g = 0; g < 4; ++g) nxt[g] = w[(size_t)((G + 1) * 4 + g) * 256];
      }
      #pragma unroll
      for (int g = 0; g < 4; g += 2) {
        dot8q(a0, a1, cur[g],     av[G * 4 + g]);
        dot8q(a2, a3, cur[g + 1], av[G * 4 + g + 1]);
      }
    }
  }
  float a = (a0 + a1) + (a2 + a3);
  if (q < 2) (q ? zs : rs)[c] = sigm(a + Brz);
  __syncthreads();                 // rs/zs ready
  if (q == 2)
    outH[c] = f2h((1.f - zs[c]) * tanhf(a + Bni + rs[c] * Bnh));
  __syncthreads();                 // outH ready
}

// ---------------- phase C: decoder scan, 1024 threads, one block per batch row ----------------
__launch_bounds__(1024, 4)
__global__ void decoderk(const float* __restrict__ x, const u16* __restrict__ memH,
                         const u16* __restrict__ W0T, const u16* __restrict__ W1T,
                         const u16* __restrict__ W2T, const u16* __restrict__ W3T,
                         const u16* __restrict__ W4T,
                         const float* __restrict__ bi0, const float* __restrict__ bh0,
                         const float* __restrict__ bi1, const float* __restrict__ bh1,
                         const float* __restrict__ bi2, const float* __restrict__ bh2,
                         const float* __restrict__ bi3, const float* __restrict__ bh3,
                         const float* __restrict__ bi4, const float* __restrict__ bh4,
                         const float* __restrict__ Wo, const float* __restrict__ bo,
                         float* __restrict__ out) {
  const int b = blockIdx.x, tid = threadIdx.x;
  const int lane = tid & 63, wave = tid >> 6;
  const int q = tid >> 8, c = tid & 255;
  __shared__ __align__(16) u16 kstH[HID];
  __shared__ __align__(16) u16 dvH[DIM + HID];
  __shared__ __align__(16) u16 hAH[HID], hBH[HID];
  __shared__ __align__(16) float rs[HID], zs[HID];
  __shared__ __align__(16) float ppF[512];
  __shared__ __align__(16) f32x4v pvp4[16][64];
  __shared__ float red2[16];

  float Brz[5] = {0,0,0,0,0}, Bni[5] = {0,0,0,0,0}, Bnh[5] = {0,0,0,0,0};
  if (q < 2) {
    int rw = q * HID + c;
    Brz[0] = bi0[rw] + bh0[rw]; Brz[1] = bi1[rw] + bh1[rw]; Brz[2] = bi2[rw] + bh2[rw];
    Brz[3] = bi3[rw] + bh3[rw]; Brz[4] = bi4[rw] + bh4[rw];
  } else if (q == 2) {
    int rw = 2 * HID + c;
    Bni[0] = bi0[rw]; Bnh[0] = bh0[rw]; Bni[1] = bi1[rw]; Bnh[1] = bh1[rw];
    Bni[2] = bi2[rw]; Bnh[2] = bh2[rw]; Bni[3] = bi3[rw]; Bnh[3] = bh3[rw];
    Bni[4] = bi4[rw]; Bnh[4] = bh4[rw];
  }
  float wo0 = 0.f, wo1 = 0.f, wo2 = 0.f, wo3 = 0.f;
  const float bo0 = bo[0];
  if (wave == 0) { wo0 = Wo[lane]; wo1 = Wo[64+lane]; wo2 = Wo[128+lane]; wo3 = Wo[192+lane]; }
  if (tid < HID) kstH[tid] = 0;
  __syncthreads();

  const u16* mb = memH + (size_t)b * SEQT * HID;
  const int p = tid >> 1, hf = tid & 1;      // scores
  const int sg = tid >> 6, cq = tid & 63;    // PV: position-16th, 4-col quad

  for (int t = 0; t < SEQT; ++t) {
    float xr = 0.f;
    if (tid < DIM)
      xr = __builtin_nontemporal_load(x + ((size_t)b * SEQT + t) * DIM + tid);

    // ---- scores (no-max softmax): thread = (position p, half hf), ping-pong ----
    float s0 = 0.f, s1 = 0.f, s2 = 0.f, s3 = 0.f;
    {
      const u32x4v* mr = (const u32x4v*)(mb + (size_t)p * HID) + hf * 16;
      const u32x4v* kq = ((const u32x4v*)kstH) + hf * 16;
      u32x4v mA[4], mB[4];
      #pragma unroll
      for (int g = 0; g < 4; ++g) mA[g] = mr[g];
      #pragma unroll
      for (int G = 0; G < 4; ++G) {
        u32x4v* cur = (G & 1) ? mB : mA;
        u32x4v* nxt = (G & 1) ? mA : mB;
        if (G < 3) {
          #pragma unroll
          for (int g = 0; g < 4; ++g) nxt[g] = mr[(G + 1) * 4 + g];
        }
        #pragma unroll
        for (int g = 0; g < 4; g += 2) {
          dot8q(s0, s1, cur[g],     kq[G * 4 + g]);
          dot8q(s2, s3, cur[g + 1], kq[G * 4 + g + 1]);
        }
      }
    }
    float s = (s0 + s1) + (s2 + s3);
    s += __shfl_xor(s, 1);
    float pw = __expf(s);
    if (!hf) ppF[p] = pw;
    float ls = hf ? 0.f : pw;
    #pragma unroll
    for (int off = 32; off; off >>= 1) ls += __shfl_xor(ls, off);
    if (lane == 0) red2[wave] = ls;
    if (tid < DIM) dvH[tid] = f2h(xr);
    __syncthreads();               // S2: ppF, red2, dv-x

    // ---- PV: thread = (sg, cq): 4 cols, 32 positions (two interleaved 16-halves) ----
    {
      const u32x2v* mc = (const u32x2v*)mb;
      const float* ppg = ppF + sg * 32;
      float cA0=0.f,cA1=0.f,cA2=0.f,cA3=0.f, cB0=0.f,cB1=0.f,cB2=0.f,cB3=0.f;
      #pragma unroll 4
      for (int pj = 0; pj < 16; ++pj) {
        u32x2v vA = mc[(size_t)(sg * 32 + pj) * 64 + cq];
        u32x2v vB = mc[(size_t)(sg * 32 + 16 + pj) * 64 + cq];
        float wA = ppg[pj], wB = ppg[16 + pj];
        f16x2 a0 = __builtin_bit_cast(f16x2, vA.x), a1 = __builtin_bit_cast(f16x2, vA.y);
        f16x2 b0 = __builtin_bit_cast(f16x2, vB.x), b1 = __builtin_bit_cast(f16x2, vB.y);
        cA0 += wA * (float)a0[0]; cA1 += wA * (float)a0[1];
        cA2 += wA * (float)a1[0]; cA3 += wA * (float)a1[1];
        cB0 += wB * (float)b0[0]; cB1 += wB * (float)b0[1];
        cB2 += wB * (float)b1[0]; cB3 += wB * (float)b1[1];
      }
      f32x4v r;
      r.x = cA0 + cB0; r.y = cA1 + cB1; r.z = cA2 + cB2; r.w = cA3 + cB3;
      pvp4[sg][cq] = r;
    }
    __syncthreads();               // S3: pvp
    if (tid < HID) {
      float lsum = red2[0];
      #pragma unroll
      for (int i = 1; i < 16; ++i) lsum += red2[i];
      const float* pv = (const float*)pvp4;
      float ctx = 0.f;
      #pragma unroll
      for (int i = 0; i < 16; ++i) ctx += pv[i * 256 + tid];
      dvH[DIM + tid] = f2h(ctx / lsum);
    }
    __syncthreads();               // S4: dv complete

    // ---- 5 feed-forward GRU cells ----
    cellT<DIM + HID>(dvH, hAH, W0T, q, c, Brz[0], Bni[0], Bnh[0], rs, zs);
    cellT<HID>(hAH, hBH, W1T, q, c, Brz[1], Bni[1], Bnh[1], rs, zs);
    cellT<HID>(hBH, hAH, W2T, q, c, Brz[2], Bni[2], Bnh[2], rs, zs);
    cellT<HID>(hAH, hBH, W3T, q, c, Brz[3], Bni[3], Bnh[3], rs, zs);
    cellT<HID>(hBH, kstH, W4T, q, c, Brz[4], Bni[4], Bnh[4], rs, zs);

    // ---- output layer (wave 0) ----
    if (wave == 0) {
      float acc = h2f(kstH[lane]) * wo0 + h2f(kstH[64 + lane]) * wo1 +
                  h2f(kstH[128 + lane]) * wo2 + h2f(kstH[192 + lane]) * wo3;
      #pragma unroll
      for (int off = 32; off; off >>= 1) acc += __shfl_xor(acc, off);
      if (lane == 0) out[(size_t)b * SEQT + t] = sigm(acc + bo0);
    }
  }
}

// ---------------- host ----------------
extern "C" void kernel_launch(void* const* d_in, const int* in_sizes, int n_in,
                              void* d_out, int out_size, void* d_ws, size_t ws_size,
                              hipStream_t stream) {
  const float* x    = (const float*)d_in[0];
  const float* Wmi  = (const float*)d_in[1];
  const float* Wmh  = (const float*)d_in[2];
  const float* bmi  = (const float*)d_in[3];
  const float* bmh  = (const float*)d_in[4];
  const float* Wd0  = (const float*)d_in[5];
  const float* bi0  = (const float*)d_in[6];
  const float* bh0  = (const float*)d_in[7];
  const float* Wd1  = (const float*)d_in[8];
  const float* bi1  = (const float*)d_in[9];
  const float* bh1  = (const float*)d_in[10];
  const float* Wd2  = (const float*)d_in[11];
  const float* bi2  = (const float*)d_in[12];
  const float* bh2  = (const float*)d_in[13];
  const float* Wk0  = (const float*)d_in[14];
  const float* bik0 = (const float*)d_in[15];
  const float* bhk0 = (const float*)d_in[16];
  const float* Wk1  = (const float*)d_in[17];
  const float* bik1 = (const float*)d_in[18];
  const float* bhk1 = (const float*)d_in[19];
  const float* Wo   = (const float*)d_in[20];
  const float* bo   = (const float*)d_in[21];

  u16* mem = (u16*)d_ws;
  size_t off = (size_t)BATCH * SEQT * HID;     // u16 units
  u16* WmiT = mem + off; off += (size_t)G3 * DIM;
  u16* WmhT = mem + off; off += (size_t)G3 * HID;
  u16* W0T  = mem + off; off += (size_t)G3 * (DIM + HID);
  u16* W1T  = mem + off; off += (size_t)G3 * HID;
  u16* W2T  = mem + off; off += (size_t)G3 * HID;
  u16* W3T  = mem + off; off += (size_t)G3 * HID;
  u16* W4T  = mem + off; off += (size_t)G3 * HID;
  (void)ws_size; (void)in_sizes; (void)n_in; (void)out_size;

  // chunk-major f16 weight transposes
  convertT<<<(G3*DIM + 255) / 256, 256, 0, stream>>>(Wmi, WmiT, DIM, DIM/8, G3*DIM);
  convertT<<<(G3*HID + 255) / 256, 256, 0, stream>>>(Wmh, WmhT, HID, HID/8, G3*HID);
  convertT<<<(G3*(DIM+HID) + 255) / 256, 256, 0, stream>>>(Wd0, W0T, DIM+HID, (DIM+HID)/8, G3*(DIM+HID));
  convertT<<<(G3*HID + 255) / 256, 256, 0, stream>>>(Wd1, W1T, HID, HID/8, G3*HID);
  convertT<<<(G3*HID + 255) / 256, 256, 0, stream>>>(Wd2, W2T, HID, HID/8, G3*HID);
  convertT<<<(G3*HID + 255) / 256, 256, 0, stream>>>(Wk0, W3T, HID, HID/8, G3*HID);
  convertT<<<(G3*HID + 255) / 256, 256, 0, stream>>>(Wk1, W4T, HID, HID/8, G3*HID);

  gru_memk<<<BATCH, 768, 0, stream>>>(x, WmiT, WmhT, bmi, bmh, mem);
  decoderk<<<BATCH, 1024, 0, stream>>>(x, mem, W0T, W1T, W2T, W3T, W4T,
                                       bi0, bh0, bi1, bh1, bi2, bh2,
                                       bik0, bhk0, bik1, bhk1, Wo, bo,
                                       (float*)d_out);
}

// Round 10
// 33322.198 us; speedup vs baseline: 1.9569x; 1.8548x over previous
//
#include <hip/hip_runtime.h>
#include <stdint.h>

#define BATCH 256
#define SEQT  512
#define DIM   128
#define HID   256
#define G3    768   // 3*HID

typedef unsigned short u16;
typedef unsigned int   u32;
typedef _Float16 f16;
typedef f16 f16x2 __attribute__((ext_vector_type(2)));
typedef u32 u32x2v __attribute__((ext_vector_type(2)));
typedef u32 u32x4v __attribute__((ext_vector_type(4)));
typedef float f32x4v __attribute__((ext_vector_type(4)));

static __device__ __forceinline__ u16 f2h(float f) {
  f16 h = (f16)f; return __builtin_bit_cast(u16, h);
}
static __device__ __forceinline__ float h2f(u16 u) {
  return (float)__builtin_bit_cast(f16, u);
}
static __device__ __forceinline__ float sigm(float v) {
  return 1.f / (1.f + __expf(-v));
}

// 2-MAC f16 dot with f32 accumulate
static __device__ __forceinline__ float dot2f(u32 a, u32 b, float acc) {
#if __has_builtin(__builtin_amdgcn_fdot2)
  return __builtin_amdgcn_fdot2(__builtin_bit_cast(f16x2, a),
                                __builtin_bit_cast(f16x2, b), acc, false);
#else
  f16x2 av = __builtin_bit_cast(f16x2, a), bv = __builtin_bit_cast(f16x2, b);
  return acc + (float)av[0] * (float)bv[0] + (float)av[1] * (float)bv[1];
#endif
}
// 8 MACs, dual accumulator
static __device__ __forceinline__ void dot8q(float& a0, float& a1, u32x4v w, u32x4v a) {
  a0 = dot2f(w.x, a.x, a0);
  a1 = dot2f(w.y, a.y, a1);
  a0 = dot2f(w.z, a.z, a0);
  a1 = dot2f(w.w, a.w, a1);
}

// ---------------- weight fp32 -> f16, chunk-major transpose ----------------
// dst[((q*chunks + j)*256 + c)*8 + e] = f16( src[(q*256+c)*IN + j*8 + e] )
__global__ void convertT(const float* __restrict__ src, u16* __restrict__ dst,
                         int IN, int chunks, int total) {
  int t = blockIdx.x * 256 + threadIdx.x;
  if (t >= total) return;
  int e = t & 7, c = (t >> 3) & 255, r = t >> 11;
  int j = r % chunks, q = r / chunks;
  dst[t] = f2h(src[(size_t)(q * 256 + c) * IN + j * 8 + e]);
}

// ---------------- phase B: memory GRU, 768 threads, one block per batch row ----------------
__launch_bounds__(768)
__global__ void gru_memk(const float* __restrict__ x,
                         const u16* __restrict__ WiT, const u16* __restrict__ WhT,
                         const float* __restrict__ bmi, const float* __restrict__ bmh,
                         u16* __restrict__ mem) {
  const int b = blockIdx.x, tid = threadIdx.x;
  const int q = tid >> 8, c = tid & 255;
  __shared__ __align__(16) u16 xsH[DIM];
  __shared__ __align__(16) u16 hsH[HID];
  __shared__ __align__(16) float rs[HID], zs[HID];

  float Brz = 0.f, Bni = 0.f, Bnh = 0.f;
  if (q < 2) { int rw = q * HID + c; Brz = bmi[rw] + bmh[rw]; }
  else       { int rw = 2 * HID + c; Bni = bmi[rw]; Bnh = bmh[rw]; }
  const u32x4v* wi = (const u32x4v*)WiT + (size_t)q * (DIM / 8) * 256 + c;
  const u32x4v* wh = (const u32x4v*)WhT + (size_t)q * (HID / 8) * 256 + c;
  float hprev = 0.f;
  if (tid < HID) hsH[tid] = 0;
  __syncthreads();

  for (int t = 0; t < SEQT; ++t) {
    if (tid < DIM)
      xsH[tid] = f2h(__builtin_nontemporal_load(x + ((size_t)b * SEQT + t) * DIM + tid));
    __syncthreads();               // xsH ready; hsH stable
    float a0 = 0.f, a1 = 0.f, a2 = 0.f, a3 = 0.f;
    {
      const u32x4v* xa = (const u32x4v*)xsH;
      #pragma unroll 4
      for (int j = 0; j < DIM / 8; j += 2) {
        dot8q(a0, a1, wi[(size_t)j * 256], xa[j]);
        dot8q(a2, a3, wi[(size_t)(j + 1) * 256], xa[j + 1]);
      }
    }
    float ax = (a0 + a1) + (a2 + a3);
    a0 = a1 = a2 = a3 = 0.f;
    {
      const u32x4v* ha = (const u32x4v*)hsH;
      #pragma unroll 4
      for (int j = 0; j < HID / 8; j += 2) {
        dot8q(a0, a1, wh[(size_t)j * 256], ha[j]);
        dot8q(a2, a3, wh[(size_t)(j + 1) * 256], ha[j + 1]);
      }
    }
    float ah = (a0 + a1) + (a2 + a3);
    if (q < 2) (q ? zs : rs)[c] = sigm(ax + ah + Brz);
    __syncthreads();               // rs/zs ready; hsH reads done
    if (q == 2) {
      float nn = tanhf(ax + Bni + rs[c] * (ah + Bnh));
      float h = (1.f - zs[c]) * nn + zs[c] * hprev;
      hprev = h;
      hsH[c] = f2h(h);
      __builtin_nontemporal_store(f2h(h), mem + ((size_t)b * SEQT + t) * HID + c);
    }
    __syncthreads();               // hsH ready
  }
}

// ---------------- decoder feed-forward cell (round-6 shape, 4 accumulators) ----------------
template <int IN>
static __device__ __forceinline__ void cellT(const u16* __restrict__ inH,
                                             u16* __restrict__ outH,
                                             const u16* __restrict__ WT,
                                             int q, int c,
                                             float Brz, float Bni, float Bnh,
                                             float* __restrict__ rs, float* __restrict__ zs) {
  constexpr int CH = IN / 8;       // chunks per gate row
  float a0 = 0.f, a1 = 0.f, a2 = 0.f, a3 = 0.f;
  if (q < 3) {
    const u32x4v* w = (const u32x4v*)WT + (size_t)q * CH * 256 + c;
    const u32x4v* av = (const u32x4v*)inH;
    #pragma unroll 4
    for (int j = 0; j < CH; j += 2) {
      dot8q(a0, a1, w[(size_t)j * 256], av[j]);
      dot8q(a2, a3, w[(size_t)(j + 1) * 256], av[j + 1]);
    }
  }
  float a = (a0 + a1) + (a2 + a3);
  if (q < 2) (q ? zs : rs)[c] = sigm(a + Brz);
  __syncthreads();                 // rs/zs ready
  if (q == 2)
    outH[c] = f2h((1.f - zs[c]) * tanhf(a + Bni + rs[c] * Bnh));
  __syncthreads();                 // outH ready
}

// ---------------- phase C: decoder scan, 1024 threads, one block per batch row ----------------
__launch_bounds__(1024)
__global__ void decoderk(const float* __restrict__ x, const u16* __restrict__ memH,
                         const u16* __restrict__ W0T, const u16* __restrict__ W1T,
                         const u16* __restrict__ W2T, const u16* __restrict__ W3T,
                         const u16* __restrict__ W4T,
                         const float* __restrict__ bi0, const float* __restrict__ bh0,
                         const float* __restrict__ bi1, const float* __restrict__ bh1,
                         const float* __restrict__ bi2, const float* __restrict__ bh2,
                         const float* __restrict__ bi3, const float* __restrict__ bh3,
                         const float* __restrict__ bi4, const float* __restrict__ bh4,
                         const float* __restrict__ Wo, const float* __restrict__ bo,
                         float* __restrict__ out) {
  const int b = blockIdx.x, tid = threadIdx.x;
  const int lane = tid & 63, wave = tid >> 6;
  const int q = tid >> 8, c = tid & 255;
  __shared__ __align__(16) u16 kstH[HID];
  __shared__ __align__(16) u16 dvH[DIM + HID];
  __shared__ __align__(16) u16 hAH[HID], hBH[HID];
  __shared__ __align__(16) float rs[HID], zs[HID];
  __shared__ __align__(16) float ppF[512];
  __shared__ __align__(16) f32x4v pvp4[16][64];
  __shared__ float red2[16];

  float Brz[5] = {0,0,0,0,0}, Bni[5] = {0,0,0,0,0}, Bnh[5] = {0,0,0,0,0};
  if (q < 2) {
    int rw = q * HID + c;
    Brz[0] = bi0[rw] + bh0[rw]; Brz[1] = bi1[rw] + bh1[rw]; Brz[2] = bi2[rw] + bh2[rw];
    Brz[3] = bi3[rw] + bh3[rw]; Brz[4] = bi4[rw] + bh4[rw];
  } else if (q == 2) {
    int rw = 2 * HID + c;
    Bni[0] = bi0[rw]; Bnh[0] = bh0[rw]; Bni[1] = bi1[rw]; Bnh[1] = bh1[rw];
    Bni[2] = bi2[rw]; Bnh[2] = bh2[rw]; Bni[3] = bi3[rw]; Bnh[3] = bh3[rw];
    Bni[4] = bi4[rw]; Bnh[4] = bh4[rw];
  }
  float wo0 = 0.f, wo1 = 0.f, wo2 = 0.f, wo3 = 0.f;
  const float bo0 = bo[0];
  if (wave == 0) { wo0 = Wo[lane]; wo1 = Wo[64+lane]; wo2 = Wo[128+lane]; wo3 = Wo[192+lane]; }
  if (tid < HID) kstH[tid] = 0;
  __syncthreads();

  const u16* mb = memH + (size_t)b * SEQT * HID;
  const int p = tid >> 1, hf = tid & 1;      // scores
  const int sg = tid >> 6, cq = tid & 63;    // PV: position-16th, 4-col quad

  for (int t = 0; t < SEQT; ++t) {
    float xr = 0.f;
    if (tid < DIM)
      xr = __builtin_nontemporal_load(x + ((size_t)b * SEQT + t) * DIM + tid);

    // ---- scores (no-max softmax): thread = (position p, half hf); nt mem loads ----
    float s0 = 0.f, s1 = 0.f, s2 = 0.f, s3 = 0.f;
    {
      const u32x4v* mr = (const u32x4v*)(mb + (size_t)p * HID) + hf * 16;
      const u32x4v* kq = ((const u32x4v*)kstH) + hf * 16;
      #pragma unroll 4
      for (int j = 0; j < 16; j += 2) {
        u32x4v mA = __builtin_nontemporal_load(mr + j);
        u32x4v mB = __builtin_nontemporal_load(mr + j + 1);
        dot8q(s0, s1, mA, kq[j]);
        dot8q(s2, s3, mB, kq[j + 1]);
      }
    }
    float s = (s0 + s1) + (s2 + s3);
    s += __shfl_xor(s, 1);
    float pw = __expf(s);
    if (!hf) ppF[p] = pw;
    float ls = hf ? 0.f : pw;
    #pragma unroll
    for (int off = 32; off; off >>= 1) ls += __shfl_xor(ls, off);
    if (lane == 0) red2[wave] = ls;
    if (tid < DIM) dvH[tid] = f2h(xr);
    __syncthreads();               // S2: ppF, red2, dv-x

    // ---- PV: thread = (sg, cq): 4 cols, 32 positions; nt mem loads ----
    {
      const u32x2v* mc = (const u32x2v*)mb;
      const float* ppg = ppF + sg * 32;
      float cA0=0.f,cA1=0.f,cA2=0.f,cA3=0.f, cB0=0.f,cB1=0.f,cB2=0.f,cB3=0.f;
      #pragma unroll 4
      for (int pj = 0; pj < 16; ++pj) {
        u32x2v vA = __builtin_nontemporal_load(mc + (size_t)(sg * 32 + pj) * 64 + cq);
        u32x2v vB = __builtin_nontemporal_load(mc + (size_t)(sg * 32 + 16 + pj) * 64 + cq);
        float wA = ppg[pj], wB = ppg[16 + pj];
        f16x2 a0 = __builtin_bit_cast(f16x2, vA.x), a1 = __builtin_bit_cast(f16x2, vA.y);
        f16x2 b0 = __builtin_bit_cast(f16x2, vB.x), b1 = __builtin_bit_cast(f16x2, vB.y);
        cA0 += wA * (float)a0[0]; cA1 += wA * (float)a0[1];
        cA2 += wA * (float)a1[0]; cA3 += wA * (float)a1[1];
        cB0 += wB * (float)b0[0]; cB1 += wB * (float)b0[1];
        cB2 += wB * (float)b1[0]; cB3 += wB * (float)b1[1];
      }
      f32x4v r;
      r.x = cA0 + cB0; r.y = cA1 + cB1; r.z = cA2 + cB2; r.w = cA3 + cB3;
      pvp4[sg][cq] = r;
    }
    __syncthreads();               // S3: pvp
    if (tid < HID) {
      float lsum = red2[0];
      #pragma unroll
      for (int i = 1; i < 16; ++i) lsum += red2[i];
      const float* pv = (const float*)pvp4;
      float ctx = 0.f;
      #pragma unroll
      for (int i = 0; i < 16; ++i) ctx += pv[i * 256 + tid];
      dvH[DIM + tid] = f2h(ctx / lsum);
    }
    __syncthreads();               // S4: dv complete

    // ---- 5 feed-forward GRU cells ----
    cellT<DIM + HID>(dvH, hAH, W0T, q, c, Brz[0], Bni[0], Bnh[0], rs, zs);
    cellT<HID>(hAH, hBH, W1T, q, c, Brz[1], Bni[1], Bnh[1], rs, zs);
    cellT<HID>(hBH, hAH, W2T, q, c, Brz[2], Bni[2], Bnh[2], rs, zs);
    cellT<HID>(hAH, hBH, W3T, q, c, Brz[3], Bni[3], Bnh[3], rs, zs);
    cellT<HID>(hBH, kstH, W4T, q, c, Brz[4], Bni[4], Bnh[4], rs, zs);

    // ---- output layer (wave 0) ----
    if (wave == 0) {
      float acc = h2f(kstH[lane]) * wo0 + h2f(kstH[64 + lane]) * wo1 +
                  h2f(kstH[128 + lane]) * wo2 + h2f(kstH[192 + lane]) * wo3;
      #pragma unroll
      for (int off = 32; off; off >>= 1) acc += __shfl_xor(acc, off);
      if (lane == 0) out[(size_t)b * SEQT + t] = sigm(acc + bo0);
    }
  }
}

// ---------------- host ----------------
extern "C" void kernel_launch(void* const* d_in, const int* in_sizes, int n_in,
                              void* d_out, int out_size, void* d_ws, size_t ws_size,
                              hipStream_t stream) {
  const float* x    = (const float*)d_in[0];
  const float* Wmi  = (const float*)d_in[1];
  const float* Wmh  = (const float*)d_in[2];
  const float* bmi  = (const float*)d_in[3];
  const float* bmh  = (const float*)d_in[4];
  const float* Wd0  = (const float*)d_in[5];
  const float* bi0  = (const float*)d_in[6];
  const float* bh0  = (const float*)d_in[7];
  const float* Wd1  = (const float*)d_in[8];
  const float* bi1  = (const float*)d_in[9];
  const float* bh1  = (const float*)d_in[10];
  const float* Wd2  = (const float*)d_in[11];
  const float* bi2  = (const float*)d_in[12];
  const float* bh2  = (const float*)d_in[13];
  const float* Wk0  = (const float*)d_in[14];
  const float* bik0 = (const float*)d_in[15];
  const float* bhk0 = (const float*)d_in[16];
  const float* Wk1  = (const float*)d_in[17];
  const float* bik1 = (const float*)d_in[18];
  const float* bhk1 = (const float*)d_in[19];
  const float* Wo   = (const float*)d_in[20];
  const float* bo   = (const float*)d_in[21];

  u16* mem = (u16*)d_ws;
  size_t off = (size_t)BATCH * SEQT * HID;     // u16 units
  u16* WmiT = mem + off; off += (size_t)G3 * DIM;
  u16* WmhT = mem + off; off += (size_t)G3 * HID;
  u16* W0T  = mem + off; off += (size_t)G3 * (DIM + HID);
  u16* W1T  = mem + off; off += (size_t)G3 * HID;
  u16* W2T  = mem + off; off += (size_t)G3 * HID;
  u16* W3T  = mem + off; off += (size_t)G3 * HID;
  u16* W4T  = mem + off; off += (size_t)G3 * HID;
  (void)ws_size; (void)in_sizes; (void)n_in; (void)out_size;

  // chunk-major f16 weight transposes
  convertT<<<(G3*DIM + 255) / 256, 256, 0, stream>>>(Wmi, WmiT, DIM, DIM/8, G3*DIM);
  convertT<<<(G3*HID + 255) / 256, 256, 0, stream>>>(Wmh, WmhT, HID, HID/8, G3*HID);
  convertT<<<(G3*(DIM+HID) + 255) / 256, 256, 0, stream>>>(Wd0, W0T, DIM+HID, (DIM+HID)/8, G3*(DIM+HID));
  convertT<<<(G3*HID + 255) / 256, 256, 0, stream>>>(Wd1, W1T, HID, HID/8, G3*HID);
  convertT<<<(G3*HID + 255) / 256, 256, 0, stream>>>(Wd2, W2T, HID, HID/8, G3*HID);
  convertT<<<(G3*HID + 255) / 256, 256, 0, stream>>>(Wk0, W3T, HID, HID/8, G3*HID);
  convertT<<<(G3*HID + 255) / 256, 256, 0, stream>>>(Wk1, W4T, HID, HID/8, G3*HID);

  gru_memk<<<BATCH, 768, 0, stream>>>(x, WmiT, WmhT, bmi, bmh, mem);
  decoderk<<<BATCH, 1024, 0, stream>>>(x, mem, W0T, W1T, W2T, W3T, W4T,
                                       bi0, bh0, bi1, bh1, bi2, bh2,
                                       bik0, bhk0, bik1, bhk1, Wo, bo,
                                       (float*)d_out);
}